// Round 12
// baseline (238.131 us; speedup 1.0000x reference)
//
#include <hip/hip_runtime.h>
#include <stdint.h>

#define T_SEQ 2048
#define B_SZ 2
#define N_HEAD 16
#define D_HEAD 128
#define C_DIM 2048
#define M_ROWS (B_SZ*T_SEQ)   // 4096
#define N_BH (B_SZ*N_HEAD)    // 32

typedef _Float16 f16;
typedef f16 f16x8 __attribute__((ext_vector_type(8)));
typedef f16 f16x4 __attribute__((ext_vector_type(4)));
typedef float f32x4 __attribute__((ext_vector_type(4)));

#define MFMA_F16(a,b,c) __builtin_amdgcn_mfma_f32_16x16x32_f16(a,b,c,0,0,0)

#define BAR_LGKM() do { asm volatile("s_waitcnt lgkmcnt(0)" ::: "memory"); \
                        __builtin_amdgcn_s_barrier(); } while (0)
#define BAR_ALL()  do { asm volatile("s_waitcnt vmcnt(0) lgkmcnt(0)" ::: "memory"); \
                        __builtin_amdgcn_s_barrier(); } while (0)

// raw 2^x via builtin when available (compiler handles TRANS hazards);
// inline-asm fallback only if the builtin is missing.
__device__ __forceinline__ float fexp2(float x) {
#if __has_builtin(__builtin_amdgcn_exp2f)
  return __builtin_amdgcn_exp2f(x);
#else
  float r; asm("v_exp_f32 %0, %1" : "=v"(r) : "v"(x)); return r;
#endif
}

// async global->LDS, 16B per lane; LDS dest is wave-uniform base + lane*16
__device__ __forceinline__ void gl_lds16(const void* g, void* l) {
  __builtin_amdgcn_global_load_lds(
      (const __attribute__((address_space(1))) unsigned int*)g,
      (__attribute__((address_space(3))) unsigned int*)l, 16, 0, 0);
}

// 1/sqrt(128) * log2(e)  (exp2-fold: mb carries log2e so exp(att)==exp2(acc))
#define MB_SCALE 0.12752924444069595f
#define RMS_EPS  1.1920928955078125e-07f

// ---------------- prep (merged): W -> Wb,Wtb (fp16) ; x -> fp16 ------------
__global__ void k_prep(const float* __restrict__ W, const float* __restrict__ x,
                       f16* __restrict__ Wb, f16* __restrict__ Wtb,
                       f16* __restrict__ xb) {
  __shared__ float tile[64][65];
  const int lin = blockIdx.x;
  const int t = threadIdx.x;
  if (lin < 1024) {
    const int bx = (lin & 31) * 64;   // col base
    const int by = (lin >> 5) * 64;   // row base
    const int tc = t & 63, tr4 = t >> 6;
    for (int rr = tr4; rr < 64; rr += 4) {
      float v = W[(size_t)(by + rr) * C_DIM + bx + tc];
      tile[rr][tc] = v;
      Wb[(size_t)(by + rr) * C_DIM + bx + tc] = (f16)v;
    }
    __syncthreads();
    for (int rr = tr4; rr < 64; rr += 4) {
      // Wtb[n][k] = W[k][n]
      Wtb[(size_t)(bx + rr) * C_DIM + by + tc] = (f16)tile[tc][rr];
    }
  } else {
    int i = (lin - 1024) * 256 + t;
    const int stride = 2048 * 256;
    const int n4 = (M_ROWS * C_DIM) / 4;
    for (; i < n4; i += stride) {
      f32x4 v = ((const f32x4*)x)[i];
      f16x4 o; o[0]=(f16)v[0]; o[1]=(f16)v[1]; o[2]=(f16)v[2]; o[3]=(f16)v[3];
      ((f16x4*)xb)[i] = o;
    }
  }
}

// ---------------- GEMM C[M][N] = sum_k A[m][k]*B[n][k]  (B^T layout) -------
template<typename OT>
__global__ __launch_bounds__(256, 2)
void k_gemm_bt(const f16* __restrict__ A, const f16* __restrict__ Bm,
               OT* __restrict__ C, int Nd, int Kd) {
  __shared__ __align__(16) f16 As[2][128 * 64];
  __shared__ __align__(16) f16 Bs[2][128 * 64];
  const int tid = threadIdx.x;
  const int lane = tid & 63, wid = tid >> 6;
  const int lr = lane & 15, lkg = lane >> 4;
  const int wr = wid >> 1, wc = wid & 1;
  const int tm = blockIdx.y * 128, tn = blockIdx.x * 128;

  f32x4 acc[4][4];
#pragma unroll
  for (int i = 0; i < 4; ++i)
#pragma unroll
    for (int j = 0; j < 4; ++j) acc[i][j] = (f32x4){0.f, 0.f, 0.f, 0.f};

  const int nkt = Kd >> 6;

  auto stage = [&](int buf, int kt) {
    const int k0 = kt << 6;
    for (int s = 0; s < 4; ++s) {
      const int r0 = (wid * 4 + s) * 8;
      const int r = r0 + (lane >> 3);
      const int lg = ((lane & 7) ^ (r & 7)) << 3;  // logical col (elems)
      gl_lds16(A + (size_t)(tm + r) * Kd + k0 + lg, &As[buf][r0 * 64]);
      gl_lds16(Bm + (size_t)(tn + r) * Kd + k0 + lg, &Bs[buf][r0 * 64]);
    }
  };

  stage(0, 0);
  int cur = 0;
  for (int kt = 0; kt < nkt; ++kt) {
    __syncthreads();                       // staged buf[cur] ready
    if (kt + 1 < nkt) stage(cur ^ 1, kt + 1);
#pragma unroll
    for (int kk = 0; kk < 2; ++kk) {
      f16x8 a[4], b[4];
#pragma unroll
      for (int i = 0; i < 4; ++i) {
        const int ra = wr * 64 + i * 16 + lr;
        const int ga = ((kk * 4 + lkg) ^ (ra & 7)) << 3;
        a[i] = *(const f16x8*)&As[cur][ra * 64 + ga];
        const int rb = wc * 64 + i * 16 + lr;
        const int gb = ((kk * 4 + lkg) ^ (rb & 7)) << 3;
        b[i] = *(const f16x8*)&Bs[cur][rb * 64 + gb];
      }
#pragma unroll
      for (int i = 0; i < 4; ++i)
#pragma unroll
        for (int j = 0; j < 4; ++j) acc[i][j] = MFMA_F16(a[i], b[j], acc[i][j]);
    }
    cur ^= 1;
  }
#pragma unroll
  for (int i = 0; i < 4; ++i) {
    const int row0 = tm + wr * 64 + i * 16 + lkg * 4;
#pragma unroll
    for (int j = 0; j < 4; ++j) {
      const int col = tn + wc * 64 + j * 16 + lr;
#pragma unroll
      for (int r = 0; r < 4; ++r)
        C[(size_t)(row0 + r) * Nd + col] = (OT)acc[i][j][r];
    }
  }
}

// ---------------- QKV GEMM with fused RMS + transpose epilogue -------------
__global__ __launch_bounds__(256, 2)
void k_gemm_qkv(const f16* __restrict__ A, const f16* __restrict__ Bm,
                const float* __restrict__ g1, const float* __restrict__ g2,
                f16* __restrict__ nb, f16* __restrict__ mb,
                f16* __restrict__ nT) {
  __shared__ __align__(16) char smem[70656];   // 64KB staging | 34KB Cs + sc
  f16 (*As)[128 * 64] = (f16(*)[128 * 64])smem;
  f16 (*Bs)[128 * 64] = (f16(*)[128 * 64])(smem + 32768);
  f16* Cs = (f16*)smem;                        // [128][136] after reuse
  float* sc = (float*)(smem + 69632);          // [128] row scales

  const int tid = threadIdx.x;
  const int lane = tid & 63, wid = tid >> 6;
  const int lr = lane & 15, lkg = lane >> 4;
  const int wr = wid >> 1, wc = wid & 1;
  const int tm = blockIdx.y * 128;           // M rows (b*T+t)
  const int hh = blockIdx.x;                 // head
  const int tn = hh * 128;

  f32x4 acc[4][4];
#pragma unroll
  for (int i = 0; i < 4; ++i)
#pragma unroll
    for (int j = 0; j < 4; ++j) acc[i][j] = (f32x4){0.f, 0.f, 0.f, 0.f};

  auto stage = [&](int buf, int kt) {
    const int k0 = kt << 6;
    for (int s = 0; s < 4; ++s) {
      const int r0 = (wid * 4 + s) * 8;
      const int r = r0 + (lane >> 3);
      const int lg = ((lane & 7) ^ (r & 7)) << 3;
      gl_lds16(A + (size_t)(tm + r) * C_DIM + k0 + lg, &As[buf][r0 * 64]);
      gl_lds16(Bm + (size_t)(tn + r) * C_DIM + k0 + lg, &Bs[buf][r0 * 64]);
    }
  };

  stage(0, 0);
  int cur = 0;
  for (int kt = 0; kt < 32; ++kt) {
    __syncthreads();
    if (kt + 1 < 32) stage(cur ^ 1, kt + 1);
#pragma unroll
    for (int kk = 0; kk < 2; ++kk) {
      f16x8 a[4], b[4];
#pragma unroll
      for (int i = 0; i < 4; ++i) {
        const int ra = wr * 64 + i * 16 + lr;
        const int ga = ((kk * 4 + lkg) ^ (ra & 7)) << 3;
        a[i] = *(const f16x8*)&As[cur][ra * 64 + ga];
        const int rb = wc * 64 + i * 16 + lr;
        const int gb = ((kk * 4 + lkg) ^ (rb & 7)) << 3;
        b[i] = *(const f16x8*)&Bs[cur][rb * 64 + gb];
      }
#pragma unroll
      for (int i = 0; i < 4; ++i)
#pragma unroll
        for (int j = 0; j < 4; ++j) acc[i][j] = MFMA_F16(a[i], b[j], acc[i][j]);
    }
    cur ^= 1;
  }
  __syncthreads();               // done reading As/Bs; reuse smem as Cs

  // acc -> Cs[row][col] (padded 136)
#pragma unroll
  for (int i = 0; i < 4; ++i)
#pragma unroll
    for (int j = 0; j < 4; ++j)
#pragma unroll
      for (int r = 0; r < 4; ++r)
        Cs[(wr * 64 + i * 16 + lkg * 4 + r) * 136 + wc * 64 + j * 16 + lr] =
            (f16)acc[i][j][r];
  __syncthreads();

  // RMS per row: thread pair (t, t^1) owns one row; each half = 64 d
  const int row = tid >> 1, dh = tid & 1;
  f16x8 v[8];
  float ss = 0.f;
#pragma unroll
  for (int c = 0; c < 8; ++c) {
    v[c] = *(const f16x8*)&Cs[row * 136 + dh * 64 + c * 8];
#pragma unroll
    for (int e = 0; e < 8; ++e) { float f = (float)v[c][e]; ss += f * f; }
  }
  ss += __shfl_xor(ss, 1);
  const float scale = rsqrtf(ss * (1.f / 128.f) + RMS_EPS);
  if (dh == 0) sc[row] = scale;

  const int grow = tm + row;                  // global M row
  const int b = grow >> 11, ts = grow & (T_SEQ - 1);
  const size_t nbase =
      ((size_t)((b * N_HEAD + hh) * T_SEQ + ts)) * 128 + dh * 64;
#pragma unroll
  for (int c = 0; c < 8; ++c) {
    const int d0 = dh * 64 + c * 8;
    f16x8 n8, m8;
#pragma unroll
    for (int e = 0; e < 8; ++e) {
      const float nf = (float)v[c][e] * scale;
      n8[e] = (f16)nf;
      m8[e] = (f16)(nf * g1[d0 + e] * g2[d0 + e] * MB_SCALE);
    }
    *(f16x8*)&nb[nbase + c * 8] = n8;
    *(f16x8*)&mb[nbase + c * 8] = m8;
  }
  __syncthreads();               // sc[] visible

  // transpose: thread owns col d = tid>>1, row-half th = tid&1 (64 rows)
  const int dcol = tid >> 1, th = tid & 1;
  const size_t tbase =
      ((size_t)((b * N_HEAD + hh) * 128 + dcol)) * T_SEQ + (tm & (T_SEQ - 1)) +
      th * 64;
#pragma unroll
  for (int rr = 0; rr < 8; ++rr) {
    f16x8 o;
#pragma unroll
    for (int e = 0; e < 8; ++e) {
      const int trow = th * 64 + rr * 8 + e;
      o[e] = (f16)((float)Cs[trow * 136 + dcol] * sc[trow]);
    }
    *(f16x8*)&nT[tbase + rr * 8] = o;
  }
}

// ---------------- stats (triangular, FULL-width paired strips) -------------
__global__ __launch_bounds__(256, 2)
void k_stats_tri2(const f16* __restrict__ mIn, const f16* __restrict__ nIn,
                  float* __restrict__ Ssum) {
  __shared__ __align__(16) f16 Ns[2][128 * 128];   // 64KB dbuf
  const int tid = threadIdx.x, lane = tid & 63, wid = tid >> 6;
  const int lr = lane & 15, lkg = lane >> 4;
  const int wr = wid >> 1, wc = wid & 1;
  const int p = blockIdx.x >> 1, h = blockIdx.x & 1;
  const int it1 = p, it2 = 15 - p;
  const int n1 = 16 - p;                   // tiles in phase 1 (17 total)
  const int s0 = h ? 9 : 0, s1 = h ? 17 : 9;
  const int bh = blockIdx.y;
  const f16* mp = mIn + (size_t)bh * T_SEQ * 128;
  const f16* np = nIn + (size_t)bh * T_SEQ * 128;
  float* Sp = Ssum + (size_t)bh * T_SEQ;

  // full 128-row msr for current it (64 VGPR)
  f16x8 msrW[4][4];
  auto loadMsr = [&](int itv) {
#pragma unroll
    for (int i = 0; i < 4; ++i)
#pragma unroll
      for (int kk = 0; kk < 4; ++kk)
        msrW[i][kk] = *(const f16x8*)&mp[(size_t)(itv * 128 + wr * 64 + i * 16 +
                                                  lr) * 128 + (kk * 4 + lkg) * 8];
  };
  auto stageN = [&](int buf, int jt) {
#pragma unroll
    for (int s = 0; s < 8; ++s) {
      const int r0 = (wid * 8 + s) * 4;
      const int r = r0 + (lane >> 4);
      const int lg = ((lane & 15) ^ (r & 7)) << 3;
      gl_lds16(np + (size_t)(jt * 128 + r) * 128 + lg, &Ns[buf][r0 * 128]);
    }
  };

  float rsum[16];
#pragma unroll
  for (int q = 0; q < 16; ++q) rsum[q] = 0.f;
  auto flushRows = [&](int itv) {
#pragma unroll
    for (int q = 0; q < 16; ++q) {
      float v = rsum[q];
      v += __shfl_xor(v, 1); v += __shfl_xor(v, 2);
      v += __shfl_xor(v, 4); v += __shfl_xor(v, 8);
      if (lr == 0) {
        const int row = itv * 128 + wr * 64 + (q >> 2) * 16 + lkg * 4 + (q & 3);
        atomicAdd(&Sp[row], v);
      }
      rsum[q] = 0.f;
    }
  };
  auto tileOf = [&](int s) { return (s < n1) ? (it1 + s) : (it2 + (s - n1)); };
  auto itOf = [&](int s) { return (s < n1) ? it1 : it2; };

  int cur_it = itOf(s0);
  loadMsr(cur_it);
  stageN(0, tileOf(s0));
  BAR_ALL();
  int cur = 0;
  float csumP[4];          // previous tile's (shfl-reduced) col sums
  int jtP = -1;            // previous tile's jt (-1: none / diagonal: skip)

  for (int s = s0; s < s1; ++s) {
    const int itv = itOf(s);
    const int jt = tileOf(s);
    if (s + 1 < s1) stageN(cur ^ 1, tileOf(s + 1));   // next-tile DMA first
    // previous tile's col atomics (fire-and-forget; covered by this tile)
    if (jtP >= 0) {
#pragma unroll
      for (int j = 0; j < 4; ++j)
        if (lkg == 0)
          atomicAdd(&Sp[jtP * 128 + wc * 64 + j * 16 + lr], csumP[j]);
      jtP = -1;
    }
    if (itv != cur_it) { loadMsr(itv); flushRows(cur_it); cur_it = itv; }

    f32x4 acc[4][4];
#pragma unroll
    for (int i = 0; i < 4; ++i)
#pragma unroll
      for (int j = 0; j < 4; ++j) acc[i][j] = (f32x4){0.f, 0.f, 0.f, 0.f};
#pragma unroll
    for (int kk = 0; kk < 4; ++kk) {
      f16x8 b[4];
#pragma unroll
      for (int j = 0; j < 4; ++j) {
        const int rb = wc * 64 + j * 16 + lr;
        const int gb = ((kk * 4 + lkg) ^ (rb & 7)) << 3;
        b[j] = *(const f16x8*)&Ns[cur][rb * 128 + gb];
      }
#pragma unroll
      for (int i = 0; i < 4; ++i)
#pragma unroll
        for (int j = 0; j < 4; ++j)
          acc[i][j] = MFMA_F16(msrW[i][kk], b[j], acc[i][j]);
    }
    // exp + row/col partial sums
    float cs[4];
#pragma unroll
    for (int j = 0; j < 4; ++j) cs[j] = 0.f;
#pragma unroll
    for (int i = 0; i < 4; ++i)
#pragma unroll
      for (int j = 0; j < 4; ++j)
#pragma unroll
        for (int r = 0; r < 4; ++r) {
          const float e = fexp2(acc[i][j][r]);
          rsum[i * 4 + r] += e;
          cs[j] += e;
        }
    if (jt != itv) {         // off-diagonal: stash col sums for scatter
#pragma unroll
      for (int j = 0; j < 4; ++j) {
        float v = cs[j];
        v += __shfl_xor(v, 16); v += __shfl_xor(v, 32);
        csumP[j] = v;
      }
      jtP = jt;
    }
    BAR_ALL();               // next Ns staged; Ns[cur] reads done
    cur ^= 1;
  }
  // final flushes
  if (jtP >= 0) {
#pragma unroll
    for (int j = 0; j < 4; ++j)
      if (lkg == 0)
        atomicAdd(&Sp[jtP * 128 + wc * 64 + j * 16 + lr], csumP[j]);
  }
  flushRows(cur_it);
}

// ---------------- alpha = 1 / S --------------------------------------------
__global__ void k_inv(const float* __restrict__ S, float* __restrict__ alpha) {
  const int i = blockIdx.x * blockDim.x + threadIdx.x;   // 16384 threads x4
  f32x4 s = ((const f32x4*)S)[i];
  f32x4 a;
#pragma unroll
  for (int e = 0; e < 4; ++e) a[e] = 1.f / s[e];
  ((f32x4*)alpha)[i] = a;
}

// ---------------- apply (512 thr, 8 waves): P = exp2*(ai+aj); Y^T += nT P --
// wave (wj = wid>>2, wi = wid&3): QK covers (32 j x 32 i); PV covers
// (64 d x 32 i). LDS 80KB -> 2 blocks/CU -> 16 waves/CU (4/SIMD), double
// the latency hiding of the 256-thread version. alpha precomputed (k_inv).
__global__ __launch_bounds__(512, 4)
void k_apply(const f16* __restrict__ mIn, const f16* __restrict__ nIn,
             const f16* __restrict__ nTIn, const float* __restrict__ alpha,
             const float* __restrict__ g3, f16* __restrict__ yb) {
  __shared__ __align__(16) f16 Ns[2][64 * 128];   // 32KB  j-rows, 128 d
  __shared__ __align__(16) f16 Nts[2][128 * 64];  // 32KB  d-rows, 64 j
  __shared__ __align__(16) f16 Ps[128 * 64];      // 16KB  i-rows, 64 j
  const int tid = threadIdx.x, lane = tid & 63, wid = tid >> 6;
  const int lr = lane & 15, lkg = lane >> 4;
  const int wj = wid >> 2;  // QK: j-half (32) | PV: d-half (64)
  const int wi = wid & 3;   // i-quarter (32) for both
  // XCD swizzle
  const int lin = blockIdx.x + (blockIdx.y << 4);
  const int swz = ((lin & 7) << 6) + (lin >> 3);
  const int it = swz & 15, bh = swz >> 4;
  const int b = bh >> 4, hh = bh & 15;
  const f16* mp = mIn + (size_t)bh * T_SEQ * 128;
  const f16* np = nIn + (size_t)bh * T_SEQ * 128;
  const f16* ntp = nTIn + (size_t)bh * 128 * T_SEQ;
  const float* al = alpha + (size_t)bh * T_SEQ;

  // QK B-operand fragments (32 i-rows of this wave), block-constant: 16 VGPR
  f16x8 msr[2][4];
#pragma unroll
  for (int ii = 0; ii < 2; ++ii)
#pragma unroll
    for (int kk = 0; kk < 4; ++kk)
      msr[ii][kk] = *(const f16x8*)&mp[(size_t)(it * 128 + wi * 32 + ii * 16 + lr) * 128 +
                                       (kk * 4 + lkg) * 8];

  auto stageN = [&](int buf, int jt) {
#pragma unroll
    for (int s = 0; s < 2; ++s) {
      const int r0 = (wid * 2 + s) * 4;         // local j row (256B rows)
      const int r = r0 + (lane >> 4);
      const int lg = ((lane & 15) ^ (r & 7)) << 3;
      gl_lds16(np + (size_t)(jt * 64 + r) * 128 + lg, &Ns[buf][r0 * 128]);
    }
  };
  auto stageNT = [&](int buf, int jt) {
#pragma unroll
    for (int s = 0; s < 2; ++s) {
      const int r0 = (wid * 2 + s) * 8;         // d row (128B rows)
      const int r = r0 + (lane >> 3);
      const int lg = ((lane & 7) ^ (r & 7)) << 3;  // pre-swizzled source col
      gl_lds16(ntp + (size_t)r * T_SEQ + jt * 64 + lg, &Nts[buf][r0 * 64]);
    }
  };

  float ai[2];
#pragma unroll
  for (int ii = 0; ii < 2; ++ii)
    ai[ii] = al[it * 128 + wi * 32 + ii * 16 + lr];

  f32x4 yacc[4][2];
#pragma unroll
  for (int i = 0; i < 4; ++i)
#pragma unroll
    for (int j = 0; j < 2; ++j) yacc[i][j] = (f32x4){0.f, 0.f, 0.f, 0.f};

  stageN(0, 0);
  stageNT(0, 0);
  BAR_ALL();
  int cur = 0;
  for (int jt = 0; jt < 32; ++jt) {
    // aj loads FIRST (so their waitcnt doesn't force the DMA to drain early)
    float aj[8];
#pragma unroll
    for (int jj = 0; jj < 2; ++jj)
#pragma unroll
      for (int r = 0; r < 4; ++r)
        aj[jj * 4 + r] = al[jt * 64 + wj * 32 + jj * 16 + lkg * 4 + r];
    // issue ALL next-step VMEM at the top: full step of compute hides it
    if (jt < 31) { stageN(cur ^ 1, jt + 1); stageNT(cur ^ 1, jt + 1); }

    // ---- QK swapped: acc[j][i], A = Ns rows (LDS), B = msr (regs) ----
    f32x4 acc[2][2];
#pragma unroll
    for (int i = 0; i < 2; ++i)
#pragma unroll
      for (int j = 0; j < 2; ++j) acc[i][j] = (f32x4){0.f, 0.f, 0.f, 0.f};
#pragma unroll
    for (int kk = 0; kk < 4; ++kk) {
      f16x8 a[2];
#pragma unroll
      for (int jj = 0; jj < 2; ++jj) {
        const int jrow = wj * 32 + jj * 16 + lr;
        a[jj] = *(const f16x8*)&Ns[cur][jrow * 128 + (((kk * 4 + lkg) ^ (jrow & 7)) << 3)];
      }
#pragma unroll
      for (int jj = 0; jj < 2; ++jj)
#pragma unroll
        for (int ii = 0; ii < 2; ++ii)
          acc[jj][ii] = MFMA_F16(a[jj], msr[ii][kk], acc[jj][ii]);
    }

    // ---- P = exp2(att)*(ai+aj) -> Ps[i][64 j], vectorized f16x4 ----
#pragma unroll
    for (int jj = 0; jj < 2; ++jj)
#pragma unroll
      for (int ii = 0; ii < 2; ++ii) {
        f16x4 o;
#pragma unroll
        for (int r = 0; r < 4; ++r) {
          const float p = fexp2(acc[jj][ii][r]) * (ai[ii] + aj[jj * 4 + r]);
          o[r] = (f16)p;
        }
        const int il = wi * 32 + ii * 16 + lr;
        const int jl = wj * 32 + jj * 16 + lkg * 4;
        *(f16x4*)&Ps[il * 64 + (((jl >> 3) ^ (il & 7)) << 3) + (jl & 7)] = o;
      }
    BAR_LGKM();                    // Ps visible (prev PV reads already done)

    // ---- PV: yacc[d][i] += sum_j Nts[d][j] * Ps[i][j] ----
#pragma unroll
    for (int kk = 0; kk < 2; ++kk) {
      f16x8 a[4], bfr[2];
#pragma unroll
      for (int dd = 0; dd < 4; ++dd) {
        const int drow = wj * 64 + dd * 16 + lr;
        a[dd] = *(const f16x8*)&Nts[cur][drow * 64 + (((kk * 4 + lkg) ^ (drow & 7)) << 3)];
      }
#pragma unroll
      for (int ii = 0; ii < 2; ++ii) {
        const int irow = wi * 32 + ii * 16 + lr;
        bfr[ii] = *(const f16x8*)&Ps[irow * 64 + (((kk * 4 + lkg) ^ (irow & 7)) << 3)];
      }
#pragma unroll
      for (int dd = 0; dd < 4; ++dd)
#pragma unroll
        for (int ii = 0; ii < 2; ++ii)
          yacc[dd][ii] = MFMA_F16(a[dd], bfr[ii], yacc[dd][ii]);
    }
    BAR_ALL();                     // next Ns/Nts staged; Ps reads done
    cur ^= 1;
  }

  // ---- epilogue: yb[b, t=i, hh*128+d] = yacc * g3[d] ----
#pragma unroll
  for (int dd = 0; dd < 4; ++dd) {
    const int d0 = wj * 64 + dd * 16 + lkg * 4;
    float g3v[4];
#pragma unroll
    for (int r = 0; r < 4; ++r) g3v[r] = g3[d0 + r];
#pragma unroll
    for (int ii = 0; ii < 2; ++ii) {
      const int icol = wi * 32 + ii * 16 + lr;
      const size_t base =
          ((size_t)(b * T_SEQ + it * 128 + icol)) * C_DIM + hh * 128 + d0;
      f16x4 o;
#pragma unroll
      for (int r = 0; r < 4; ++r) o[r] = (f16)(yacc[dd][ii][r] * g3v[r]);
      *(f16x4*)&yb[base] = o;
    }
  }
}

// ---------------------------------------------------------------------------
extern "C" void kernel_launch(void* const* d_in, const int* in_sizes, int n_in,
                              void* d_out, int out_size, void* d_ws,
                              size_t ws_size, hipStream_t stream) {
  const float* x = (const float*)d_in[0];
  const float* W = (const float*)d_in[1];
  const float* g1 = (const float*)d_in[2];
  const float* g2 = (const float*)d_in[3];
  const float* g3 = (const float*)d_in[4];
  float* out = (float*)d_out;
  char* ws = (char*)d_ws;

  f16* xb   = (f16*)(ws);                      // 16,777,216 B
  f16* Wb   = (f16*)(ws + 16777216);           //  8,388,608
  f16* Wtb  = (f16*)(ws + 25165824);           //  8,388,608
  f16* nb   = (f16*)(ws + 50331648);           // 16,777,216
  f16* mb   = (f16*)(ws + 67108864);           // 16,777,216
  f16* nT   = (f16*)(ws + 83886080);           // 16,777,216
  f16* yb   = (f16*)(ws + 100663296);          // 16,777,216
  float* alpha = (float*)(ws + 117440512);     //    262,144
  float* Ssum  = (float*)(ws + 117702656);     //    262,144

  hipMemsetAsync(Ssum, 0, 262144, stream);
  k_prep<<<dim3(3072), 256, 0, stream>>>(W, x, Wb, Wtb, xb);
  k_gemm_qkv<<<dim3(16, 32), 256, 0, stream>>>(xb, Wb, g1, g2, nb, mb, nT);
  k_stats_tri2<<<dim3(16, 32), 256, 0, stream>>>(mb, nb, Ssum);
  k_inv<<<dim3(64), 256, 0, stream>>>(Ssum, alpha);
  k_apply<<<dim3(16, 32), 512, 0, stream>>>(mb, nb, nT, alpha, g3, yb);
  k_gemm_bt<float><<<dim3(16, 32), 256, 0, stream>>>(yb, Wtb, out, C_DIM, C_DIM);
}

// Round 13
// 224.388 us; speedup vs baseline: 1.0612x; 1.0612x over previous
//
#include <hip/hip_runtime.h>
#include <stdint.h>

#define T_SEQ 2048
#define B_SZ 2
#define N_HEAD 16
#define D_HEAD 128
#define C_DIM 2048
#define M_ROWS (B_SZ*T_SEQ)   // 4096
#define N_BH (B_SZ*N_HEAD)    // 32

typedef _Float16 f16;
typedef f16 f16x8 __attribute__((ext_vector_type(8)));
typedef f16 f16x4 __attribute__((ext_vector_type(4)));
typedef float f32x4 __attribute__((ext_vector_type(4)));

#define MFMA_F16(a,b,c) __builtin_amdgcn_mfma_f32_16x16x32_f16(a,b,c,0,0,0)

#define BAR_LGKM() do { asm volatile("s_waitcnt lgkmcnt(0)" ::: "memory"); \
                        __builtin_amdgcn_s_barrier(); } while (0)
#define BAR_ALL()  do { asm volatile("s_waitcnt vmcnt(0) lgkmcnt(0)" ::: "memory"); \
                        __builtin_amdgcn_s_barrier(); } while (0)

// raw 2^x via builtin (compiler handles TRANS hazards). R11 showed the
// unconditional inline-asm variant NaNs — keep the builtin path.
__device__ __forceinline__ float fexp2(float x) {
#if __has_builtin(__builtin_amdgcn_exp2f)
  return __builtin_amdgcn_exp2f(x);
#else
  float r; asm("v_exp_f32 %0, %1" : "=v"(r) : "v"(x)); return r;
#endif
}

// async global->LDS, 16B per lane; LDS dest is wave-uniform base + lane*16
__device__ __forceinline__ void gl_lds16(const void* g, void* l) {
  __builtin_amdgcn_global_load_lds(
      (const __attribute__((address_space(1))) unsigned int*)g,
      (__attribute__((address_space(3))) unsigned int*)l, 16, 0, 0);
}

// 1/sqrt(128) * log2(e)  (exp2-fold: mb carries log2e so exp(att)==exp2(acc))
#define MB_SCALE 0.12752924444069595f
#define RMS_EPS  1.1920928955078125e-07f

// ---------------- prep (merged): W -> Wb,Wtb (fp16) ; x -> fp16 ------------
__global__ void k_prep(const float* __restrict__ W, const float* __restrict__ x,
                       f16* __restrict__ Wb, f16* __restrict__ Wtb,
                       f16* __restrict__ xb) {
  __shared__ float tile[64][65];
  const int lin = blockIdx.x;
  const int t = threadIdx.x;
  if (lin < 1024) {
    const int bx = (lin & 31) * 64;   // col base
    const int by = (lin >> 5) * 64;   // row base
    const int tc = t & 63, tr4 = t >> 6;
    for (int rr = tr4; rr < 64; rr += 4) {
      float v = W[(size_t)(by + rr) * C_DIM + bx + tc];
      tile[rr][tc] = v;
      Wb[(size_t)(by + rr) * C_DIM + bx + tc] = (f16)v;
    }
    __syncthreads();
    for (int rr = tr4; rr < 64; rr += 4) {
      // Wtb[n][k] = W[k][n]
      Wtb[(size_t)(bx + rr) * C_DIM + by + tc] = (f16)tile[tc][rr];
    }
  } else {
    int i = (lin - 1024) * 256 + t;
    const int stride = 2048 * 256;
    const int n4 = (M_ROWS * C_DIM) / 4;
    for (; i < n4; i += stride) {
      f32x4 v = ((const f32x4*)x)[i];
      f16x4 o; o[0]=(f16)v[0]; o[1]=(f16)v[1]; o[2]=(f16)v[2]; o[3]=(f16)v[3];
      ((f16x4*)xb)[i] = o;
    }
  }
}

// ---------------- GEMM C[M][N] = sum_k A[m][k]*B[n][k]  (B^T layout) -------
template<typename OT>
__global__ __launch_bounds__(256, 2)
void k_gemm_bt(const f16* __restrict__ A, const f16* __restrict__ Bm,
               OT* __restrict__ C, int Nd, int Kd) {
  __shared__ __align__(16) f16 As[2][128 * 64];
  __shared__ __align__(16) f16 Bs[2][128 * 64];
  const int tid = threadIdx.x;
  const int lane = tid & 63, wid = tid >> 6;
  const int lr = lane & 15, lkg = lane >> 4;
  const int wr = wid >> 1, wc = wid & 1;
  const int tm = blockIdx.y * 128, tn = blockIdx.x * 128;

  f32x4 acc[4][4];
#pragma unroll
  for (int i = 0; i < 4; ++i)
#pragma unroll
    for (int j = 0; j < 4; ++j) acc[i][j] = (f32x4){0.f, 0.f, 0.f, 0.f};

  const int nkt = Kd >> 6;

  auto stage = [&](int buf, int kt) {
    const int k0 = kt << 6;
    for (int s = 0; s < 4; ++s) {
      const int r0 = (wid * 4 + s) * 8;
      const int r = r0 + (lane >> 3);
      const int lg = ((lane & 7) ^ (r & 7)) << 3;  // logical col (elems)
      gl_lds16(A + (size_t)(tm + r) * Kd + k0 + lg, &As[buf][r0 * 64]);
      gl_lds16(Bm + (size_t)(tn + r) * Kd + k0 + lg, &Bs[buf][r0 * 64]);
    }
  };

  stage(0, 0);
  int cur = 0;
  for (int kt = 0; kt < nkt; ++kt) {
    __syncthreads();                       // staged buf[cur] ready
    if (kt + 1 < nkt) stage(cur ^ 1, kt + 1);
#pragma unroll
    for (int kk = 0; kk < 2; ++kk) {
      f16x8 a[4], b[4];
#pragma unroll
      for (int i = 0; i < 4; ++i) {
        const int ra = wr * 64 + i * 16 + lr;
        const int ga = ((kk * 4 + lkg) ^ (ra & 7)) << 3;
        a[i] = *(const f16x8*)&As[cur][ra * 64 + ga];
        const int rb = wc * 64 + i * 16 + lr;
        const int gb = ((kk * 4 + lkg) ^ (rb & 7)) << 3;
        b[i] = *(const f16x8*)&Bs[cur][rb * 64 + gb];
      }
#pragma unroll
      for (int i = 0; i < 4; ++i)
#pragma unroll
        for (int j = 0; j < 4; ++j) acc[i][j] = MFMA_F16(a[i], b[j], acc[i][j]);
    }
    cur ^= 1;
  }
#pragma unroll
  for (int i = 0; i < 4; ++i) {
    const int row0 = tm + wr * 64 + i * 16 + lkg * 4;
#pragma unroll
    for (int j = 0; j < 4; ++j) {
      const int col = tn + wc * 64 + j * 16 + lr;
#pragma unroll
      for (int r = 0; r < 4; ++r)
        C[(size_t)(row0 + r) * Nd + col] = (OT)acc[i][j][r];
    }
  }
}

// ---------------- QKV GEMM with fused RMS + transpose epilogue -------------
__global__ __launch_bounds__(256, 2)
void k_gemm_qkv(const f16* __restrict__ A, const f16* __restrict__ Bm,
                const float* __restrict__ g1, const float* __restrict__ g2,
                f16* __restrict__ nb, f16* __restrict__ mb,
                f16* __restrict__ nT) {
  __shared__ __align__(16) char smem[70656];   // 64KB staging | 34KB Cs + sc
  f16 (*As)[128 * 64] = (f16(*)[128 * 64])smem;
  f16 (*Bs)[128 * 64] = (f16(*)[128 * 64])(smem + 32768);
  f16* Cs = (f16*)smem;                        // [128][136] after reuse
  float* sc = (float*)(smem + 69632);          // [128] row scales

  const int tid = threadIdx.x;
  const int lane = tid & 63, wid = tid >> 6;
  const int lr = lane & 15, lkg = lane >> 4;
  const int wr = wid >> 1, wc = wid & 1;
  const int tm = blockIdx.y * 128;           // M rows (b*T+t)
  const int hh = blockIdx.x;                 // head
  const int tn = hh * 128;

  f32x4 acc[4][4];
#pragma unroll
  for (int i = 0; i < 4; ++i)
#pragma unroll
    for (int j = 0; j < 4; ++j) acc[i][j] = (f32x4){0.f, 0.f, 0.f, 0.f};

  auto stage = [&](int buf, int kt) {
    const int k0 = kt << 6;
    for (int s = 0; s < 4; ++s) {
      const int r0 = (wid * 4 + s) * 8;
      const int r = r0 + (lane >> 3);
      const int lg = ((lane & 7) ^ (r & 7)) << 3;
      gl_lds16(A + (size_t)(tm + r) * C_DIM + k0 + lg, &As[buf][r0 * 64]);
      gl_lds16(Bm + (size_t)(tn + r) * C_DIM + k0 + lg, &Bs[buf][r0 * 64]);
    }
  };

  stage(0, 0);
  int cur = 0;
  for (int kt = 0; kt < 32; ++kt) {
    __syncthreads();
    if (kt + 1 < 32) stage(cur ^ 1, kt + 1);
#pragma unroll
    for (int kk = 0; kk < 2; ++kk) {
      f16x8 a[4], b[4];
#pragma unroll
      for (int i = 0; i < 4; ++i) {
        const int ra = wr * 64 + i * 16 + lr;
        const int ga = ((kk * 4 + lkg) ^ (ra & 7)) << 3;
        a[i] = *(const f16x8*)&As[cur][ra * 64 + ga];
        const int rb = wc * 64 + i * 16 + lr;
        const int gb = ((kk * 4 + lkg) ^ (rb & 7)) << 3;
        b[i] = *(const f16x8*)&Bs[cur][rb * 64 + gb];
      }
#pragma unroll
      for (int i = 0; i < 4; ++i)
#pragma unroll
        for (int j = 0; j < 4; ++j) acc[i][j] = MFMA_F16(a[i], b[j], acc[i][j]);
    }
    cur ^= 1;
  }
  __syncthreads();               // done reading As/Bs; reuse smem as Cs

  // acc -> Cs[row][col] (padded 136)
#pragma unroll
  for (int i = 0; i < 4; ++i)
#pragma unroll
    for (int j = 0; j < 4; ++j)
#pragma unroll
      for (int r = 0; r < 4; ++r)
        Cs[(wr * 64 + i * 16 + lkg * 4 + r) * 136 + wc * 64 + j * 16 + lr] =
            (f16)acc[i][j][r];
  __syncthreads();

  // RMS per row: thread pair (t, t^1) owns one row; each half = 64 d
  const int row = tid >> 1, dh = tid & 1;
  f16x8 v[8];
  float ss = 0.f;
#pragma unroll
  for (int c = 0; c < 8; ++c) {
    v[c] = *(const f16x8*)&Cs[row * 136 + dh * 64 + c * 8];
#pragma unroll
    for (int e = 0; e < 8; ++e) { float f = (float)v[c][e]; ss += f * f; }
  }
  ss += __shfl_xor(ss, 1);
  const float scale = rsqrtf(ss * (1.f / 128.f) + RMS_EPS);
  if (dh == 0) sc[row] = scale;

  const int grow = tm + row;                  // global M row
  const int b = grow >> 11, ts = grow & (T_SEQ - 1);
  const size_t nbase =
      ((size_t)((b * N_HEAD + hh) * T_SEQ + ts)) * 128 + dh * 64;
#pragma unroll
  for (int c = 0; c < 8; ++c) {
    const int d0 = dh * 64 + c * 8;
    f16x8 n8, m8;
#pragma unroll
    for (int e = 0; e < 8; ++e) {
      const float nf = (float)v[c][e] * scale;
      n8[e] = (f16)nf;
      m8[e] = (f16)(nf * g1[d0 + e] * g2[d0 + e] * MB_SCALE);
    }
    *(f16x8*)&nb[nbase + c * 8] = n8;
    *(f16x8*)&mb[nbase + c * 8] = m8;
  }
  __syncthreads();               // sc[] visible

  // transpose: thread owns col d = tid>>1, row-half th = tid&1 (64 rows)
  const int dcol = tid >> 1, th = tid & 1;
  const size_t tbase =
      ((size_t)((b * N_HEAD + hh) * 128 + dcol)) * T_SEQ + (tm & (T_SEQ - 1)) +
      th * 64;
#pragma unroll
  for (int rr = 0; rr < 8; ++rr) {
    f16x8 o;
#pragma unroll
    for (int e = 0; e < 8; ++e) {
      const int trow = th * 64 + rr * 8 + e;
      o[e] = (f16)((float)Cs[trow * 136 + dcol] * sc[trow]);
    }
    *(f16x8*)&nT[tbase + rr * 8] = o;
  }
}

// ---------------- stats (full): alpha_i = 1 / sum_j exp2(att_ij) -----------
__global__ __launch_bounds__(256, 2)
void k_stats(const f16* __restrict__ mIn, const f16* __restrict__ nIn,
             float* __restrict__ alpha) {
  __shared__ __align__(16) f16 Ns[2][128 * 128];   // 64KB dbuf
  __shared__ float red[256];
  const int tid = threadIdx.x, lane = tid & 63, wid = tid >> 6;
  const int lr = lane & 15, lkg = lane >> 4;
  const int wr = wid >> 1, wc = wid & 1;
  // XCD swizzle: each XCD gets 4 consecutive bh (all 16 it) for L2 locality
  const int lin = blockIdx.x + (blockIdx.y << 4);
  const int swz = ((lin & 7) << 6) + (lin >> 3);
  const int it = swz & 15, bh = swz >> 4;
  const f16* mp = mIn + (size_t)bh * T_SEQ * 128;
  const f16* np = nIn + (size_t)bh * T_SEQ * 128;

  f16x8 msr[4][4];
#pragma unroll
  for (int i = 0; i < 4; ++i)
#pragma unroll
    for (int kk = 0; kk < 4; ++kk)
      msr[i][kk] = *(const f16x8*)&mp[(size_t)(it * 128 + wr * 64 + i * 16 + lr) * 128 +
                                      (kk * 4 + lkg) * 8];

  auto stageN = [&](int buf, int jt) {
#pragma unroll
    for (int s = 0; s < 8; ++s) {
      const int r0 = (wid * 8 + s) * 4;
      const int r = r0 + (lane >> 4);
      const int lg = ((lane & 15) ^ (r & 7)) << 3;
      gl_lds16(np + (size_t)(jt * 128 + r) * 128 + lg, &Ns[buf][r0 * 128]);
    }
  };

  float srun[16];
#pragma unroll
  for (int q = 0; q < 16; ++q) srun[q] = 0.f;

  stageN(0, 0);
  BAR_ALL();
  int cur = 0;
  for (int jt = 0; jt < 16; ++jt) {
    if (jt < 15) stageN(cur ^ 1, jt + 1);   // DMA overlaps QK+exp
    f32x4 acc[4][4];
#pragma unroll
    for (int i = 0; i < 4; ++i)
#pragma unroll
      for (int j = 0; j < 4; ++j) acc[i][j] = (f32x4){0.f, 0.f, 0.f, 0.f};
#pragma unroll
    for (int kk = 0; kk < 4; ++kk) {
      f16x8 b[4];
#pragma unroll
      for (int j = 0; j < 4; ++j) {
        const int rb = wc * 64 + j * 16 + lr;
        const int gb = ((kk * 4 + lkg) ^ (rb & 7)) << 3;
        b[j] = *(const f16x8*)&Ns[cur][rb * 128 + gb];
      }
#pragma unroll
      for (int i = 0; i < 4; ++i)
#pragma unroll
        for (int j = 0; j < 4; ++j)
          acc[i][j] = MFMA_F16(msr[i][kk], b[j], acc[i][j]);
    }
#pragma unroll
    for (int i = 0; i < 4; ++i)
#pragma unroll
      for (int r = 0; r < 4; ++r) {
        float s = fexp2(acc[i][0][r]) + fexp2(acc[i][1][r]) +
                  fexp2(acc[i][2][r]) + fexp2(acc[i][3][r]);
        srun[i * 4 + r] += s;
      }
    BAR_ALL();                  // staged Ns ready; all reads of cur done
    cur ^= 1;
  }
#pragma unroll
  for (int q = 0; q < 16; ++q) {
    float v = srun[q];
    v += __shfl_xor(v, 1); v += __shfl_xor(v, 2);
    v += __shfl_xor(v, 4); v += __shfl_xor(v, 8);
    srun[q] = v;
  }
  if (lr == 0) {
#pragma unroll
    for (int q = 0; q < 16; ++q) {
      const int row = wr * 64 + (q >> 2) * 16 + lkg * 4 + (q & 3);
      red[row * 2 + wc] = srun[q];
    }
  }
  __syncthreads();
  if (tid < 128) {
    const float s = red[tid * 2] + red[tid * 2 + 1];
    alpha[(size_t)bh * T_SEQ + it * 128 + tid] = 1.f / s;
  }
}

// ---------------- apply (256 thr): P = exp2(att)*(ai+aj); Y^T += nT @ P ----
__global__ __launch_bounds__(256, 2)
void k_apply(const f16* __restrict__ mIn, const f16* __restrict__ nIn,
             const f16* __restrict__ nTIn, const float* __restrict__ alpha,
             const float* __restrict__ g3, f16* __restrict__ yb) {
  __shared__ __align__(16) f16 Ns[2][64 * 128];   // 32KB  j-rows, 128 d
  __shared__ __align__(16) f16 Nts[2][128 * 64];  // 32KB  d-rows, 64 j
  __shared__ __align__(16) f16 Ps[128 * 64];      // 16KB  i-rows, 64 j
  const int tid = threadIdx.x, lane = tid & 63, wid = tid >> 6;
  const int lr = lane & 15, lkg = lane >> 4;
  const int wj = wid >> 1;  // QK: j-half (32) | PV: d-half (64)
  const int wi = wid & 1;   // i-half (64) for both
  // XCD swizzle
  const int lin = blockIdx.x + (blockIdx.y << 4);
  const int swz = ((lin & 7) << 6) + (lin >> 3);
  const int it = swz & 15, bh = swz >> 4;
  const int b = bh >> 4, hh = bh & 15;
  const f16* mp = mIn + (size_t)bh * T_SEQ * 128;
  const f16* np = nIn + (size_t)bh * T_SEQ * 128;
  const f16* ntp = nTIn + (size_t)bh * 128 * T_SEQ;
  const float* al = alpha + (size_t)bh * T_SEQ;

  f16x8 msr[4][4];
#pragma unroll
  for (int ii = 0; ii < 4; ++ii)
#pragma unroll
    for (int kk = 0; kk < 4; ++kk)
      msr[ii][kk] = *(const f16x8*)&mp[(size_t)(it * 128 + wi * 64 + ii * 16 + lr) * 128 +
                                       (kk * 4 + lkg) * 8];

  auto stageN = [&](int buf, int jt) {
#pragma unroll
    for (int s = 0; s < 4; ++s) {
      const int r0 = (wid * 4 + s) * 4;         // local j row (256B rows)
      const int r = r0 + (lane >> 4);
      const int lg = ((lane & 15) ^ (r & 7)) << 3;
      gl_lds16(np + (size_t)(jt * 64 + r) * 128 + lg, &Ns[buf][r0 * 128]);
    }
  };
  auto stageNT = [&](int buf, int jt) {
#pragma unroll
    for (int s = 0; s < 4; ++s) {
      const int r0 = (wid * 4 + s) * 8;         // d row (128B rows)
      const int r = r0 + (lane >> 3);
      const int lg = ((lane & 7) ^ (r & 7)) << 3;  // pre-swizzled source col
      gl_lds16(ntp + (size_t)r * T_SEQ + jt * 64 + lg, &Nts[buf][r0 * 64]);
    }
  };

  float ai[4];
#pragma unroll
  for (int ii = 0; ii < 4; ++ii) ai[ii] = al[it * 128 + wi * 64 + ii * 16 + lr];

  f32x4 yacc[4][4];
#pragma unroll
  for (int i = 0; i < 4; ++i)
#pragma unroll
    for (int j = 0; j < 4; ++j) yacc[i][j] = (f32x4){0.f, 0.f, 0.f, 0.f};

  stageN(0, 0);
  stageNT(0, 0);
  BAR_ALL();
  int cur = 0;
  for (int jt = 0; jt < 32; ++jt) {
    // aj loads FIRST (so their waitcnt doesn't force the DMA to drain early)
    float aj[8];
#pragma unroll
    for (int jj = 0; jj < 2; ++jj)
#pragma unroll
      for (int r = 0; r < 4; ++r)
        aj[jj * 4 + r] = al[jt * 64 + wj * 32 + jj * 16 + lkg * 4 + r];
    // issue ALL next-step VMEM at the top: full step of compute hides it
    if (jt < 31) { stageN(cur ^ 1, jt + 1); stageNT(cur ^ 1, jt + 1); }

    // ---- QK swapped: acc[j][i], A = Ns rows (LDS), B = msr (regs) ----
    f32x4 acc[2][4];
#pragma unroll
    for (int i = 0; i < 2; ++i)
#pragma unroll
      for (int j = 0; j < 4; ++j) acc[i][j] = (f32x4){0.f, 0.f, 0.f, 0.f};
#pragma unroll
    for (int kk = 0; kk < 4; ++kk) {
      f16x8 a[2];
#pragma unroll
      for (int jj = 0; jj < 2; ++jj) {
        const int jrow = wj * 32 + jj * 16 + lr;
        a[jj] = *(const f16x8*)&Ns[cur][jrow * 128 + (((kk * 4 + lkg) ^ (jrow & 7)) << 3)];
      }
#pragma unroll
      for (int jj = 0; jj < 2; ++jj)
#pragma unroll
        for (int ii = 0; ii < 4; ++ii)
          acc[jj][ii] = MFMA_F16(a[jj], msr[ii][kk], acc[jj][ii]);
    }

    // ---- P = exp2(att)*(ai+aj) -> Ps[i][64 j], vectorized f16x4 ----
#pragma unroll
    for (int jj = 0; jj < 2; ++jj)
#pragma unroll
      for (int ii = 0; ii < 4; ++ii) {
        f16x4 o;
#pragma unroll
        for (int r = 0; r < 4; ++r) {
          const float p = fexp2(acc[jj][ii][r]) * (ai[ii] + aj[jj * 4 + r]);
          o[r] = (f16)p;
        }
        const int il = wi * 64 + ii * 16 + lr;
        const int jl = wj * 32 + jj * 16 + lkg * 4;
        *(f16x4*)&Ps[il * 64 + (((jl >> 3) ^ (il & 7)) << 3) + (jl & 7)] = o;
      }
    BAR_LGKM();                    // Ps visible (prev PV reads already done)

    // ---- PV: yacc[d][i] += sum_j Nts[d][j] * Ps[i][j] ----
#pragma unroll
    for (int kk = 0; kk < 2; ++kk) {
      f16x8 a[4], bfr[4];
#pragma unroll
      for (int dd = 0; dd < 4; ++dd) {
        const int drow = wj * 64 + dd * 16 + lr;
        a[dd] = *(const f16x8*)&Nts[cur][drow * 64 + (((kk * 4 + lkg) ^ (drow & 7)) << 3)];
      }
#pragma unroll
      for (int ii = 0; ii < 4; ++ii) {
        const int irow = wi * 64 + ii * 16 + lr;
        bfr[ii] = *(const f16x8*)&Ps[irow * 64 + (((kk * 4 + lkg) ^ (irow & 7)) << 3)];
      }
#pragma unroll
      for (int dd = 0; dd < 4; ++dd)
#pragma unroll
        for (int ii = 0; ii < 4; ++ii)
          yacc[dd][ii] = MFMA_F16(a[dd], bfr[ii], yacc[dd][ii]);
    }
    BAR_ALL();                     // next Ns/Nts staged; Ps reads done
    cur ^= 1;
  }

  // ---- epilogue: yb[b, t=i, hh*128+d] = yacc * g3[d] ----
#pragma unroll
  for (int dd = 0; dd < 4; ++dd) {
    const int d0 = wj * 64 + dd * 16 + lkg * 4;
    float g3v[4];
#pragma unroll
    for (int r = 0; r < 4; ++r) g3v[r] = g3[d0 + r];
#pragma unroll
    for (int ii = 0; ii < 4; ++ii) {
      const int icol = wi * 64 + ii * 16 + lr;
      const size_t base =
          ((size_t)(b * T_SEQ + it * 128 + icol)) * C_DIM + hh * 128 + d0;
      f16x4 o;
#pragma unroll
      for (int r = 0; r < 4; ++r) o[r] = (f16)(yacc[dd][ii][r] * g3v[r]);
      *(f16x4*)&yb[base] = o;
    }
  }
}

// ---------------------------------------------------------------------------
extern "C" void kernel_launch(void* const* d_in, const int* in_sizes, int n_in,
                              void* d_out, int out_size, void* d_ws,
                              size_t ws_size, hipStream_t stream) {
  const float* x = (const float*)d_in[0];
  const float* W = (const float*)d_in[1];
  const float* g1 = (const float*)d_in[2];
  const float* g2 = (const float*)d_in[3];
  const float* g3 = (const float*)d_in[4];
  float* out = (float*)d_out;
  char* ws = (char*)d_ws;

  f16* xb   = (f16*)(ws);                      // 16,777,216 B
  f16* Wb   = (f16*)(ws + 16777216);           //  8,388,608
  f16* Wtb  = (f16*)(ws + 25165824);           //  8,388,608
  f16* nb   = (f16*)(ws + 50331648);           // 16,777,216
  f16* mb   = (f16*)(ws + 67108864);           // 16,777,216
  f16* nT   = (f16*)(ws + 83886080);           // 16,777,216
  f16* yb   = (f16*)(ws + 100663296);          // 16,777,216
  float* alpha = (float*)(ws + 117440512);     //    262,144

  k_prep<<<dim3(3072), 256, 0, stream>>>(W, x, Wb, Wtb, xb);
  k_gemm_qkv<<<dim3(16, 32), 256, 0, stream>>>(xb, Wb, g1, g2, nb, mb, nT);
  k_stats<<<dim3(16, 32), 256, 0, stream>>>(mb, nb, alpha);
  k_apply<<<dim3(16, 32), 256, 0, stream>>>(mb, nb, nT, alpha, g3, yb);
  k_gemm_bt<float><<<dim3(16, 32), 256, 0, stream>>>(yb, Wtb, out, C_DIM, C_DIM);
}